// Round 4
// baseline (1318.662 us; speedup 1.0000x reference)
//
#include <hip/hip_runtime.h>
#include <math.h>

// Shapes (fixed by the problem)
#define NBATCH 128
#define NPTS   196     // 14*14 patches
#define DIN    768     // 3*16*16
#define DM     384
#define KCL    16
#define NEXP   8
#define NITER  10
#define NCLS   1000

// ---------------------------------------------------------------------------
// K0: init out = cb (classifier bias), zero the merge mask
// ---------------------------------------------------------------------------
__global__ __launch_bounds__(256) void init_kernel(const float* __restrict__ cb,
                                                   float* __restrict__ out,
                                                   int* __restrict__ mask) {
    int idx = blockIdx.x * 256 + threadIdx.x;
    if (idx < NBATCH * NCLS) {
        out[idx] = cb[idx % NCLS];
    } else if (idx < NBATCH * NCLS + 256) {
        mask[idx - NBATCH * NCLS] = 0;
    }
}

// ---------------------------------------------------------------------------
// K1: patch extraction + GEMM (25088x768 @ 768x384) + bias + LayerNorm + pnsq
// 512 threads, BM=64, BK=16, micro 8x6. v2: register double-buffered staging
// (prefetch tile kc+16 into regs right after barrier; LDS-write next iter).
// ---------------------------------------------------------------------------
#define BKP 16
__global__ __launch_bounds__(512, 4) void patch_ln_kernel(
        const float* __restrict__ x, const float* __restrict__ pw,
        const float* __restrict__ pb, const float* __restrict__ lng,
        const float* __restrict__ lnb, float* __restrict__ pn,
        float* __restrict__ pnsq) {
    __shared__ float As[BKP * 68];   // [kk][row], 64 rows + 4 pad
    __shared__ float Ws[BKP * DM];   // [kk][col]
    const int tid = threadIdx.x;
    const int m0  = blockIdx.x * 64;
    const int rg  = tid >> 6;        // 8 row-groups of 8 rows (one wave each)
    const int cg  = tid & 63;        // 64 col-groups; cols cg + 64j
    // A-stage mapping (first 256 threads): 64 loader rows x 4 k-quads
    const int lr = (tid & 255) >> 2, kq = tid & 3;
    const int m  = m0 + lr;
    const int bi = m / NPTS, n = m - bi * NPTS;
    const int nh = n / 14, nwp = n - nh * 14;
    const float* xb = x + (size_t)bi * 150528 + (size_t)(nh * 16) * 224 + nwp * 16;

    float acc[8][6];
#pragma unroll
    for (int r = 0; r < 8; ++r)
#pragma unroll
        for (int j = 0; j < 6; ++j) acc[r][j] = 0.f;

    const float4* pw4 = (const float4*)pw;
    // prefetch tile 0 into regs
    float4 xv = make_float4(0.f, 0.f, 0.f, 0.f);
    float4 wv0, wv1, wv2;
    if (tid < 256) {
        int k = kq * 4;
        int c = k >> 8, py = (k >> 4) & 15, px = k & 15;
        xv = *(const float4*)(xb + c * 50176 + py * 224 + px);
    }
    wv0 = pw4[tid];
    wv1 = pw4[tid + 512];
    wv2 = pw4[tid + 1024];

    for (int kc = 0; kc < DIN; kc += BKP) {
        // commit prefetched regs to LDS
        if (tid < 256) {
            As[(kq * 4 + 0) * 68 + lr] = xv.x;
            As[(kq * 4 + 1) * 68 + lr] = xv.y;
            As[(kq * 4 + 2) * 68 + lr] = xv.z;
            As[(kq * 4 + 3) * 68 + lr] = xv.w;
        }
        ((float4*)Ws)[tid]        = wv0;
        ((float4*)Ws)[tid + 512]  = wv1;
        ((float4*)Ws)[tid + 1024] = wv2;
        __syncthreads();
        // prefetch next tile (overlaps with compute below)
        const int kn = kc + BKP;
        if (kn < DIN) {
            if (tid < 256) {
                int k = kn + kq * 4;
                int c = k >> 8, py = (k >> 4) & 15, px = k & 15;
                xv = *(const float4*)(xb + c * 50176 + py * 224 + px);
            }
            wv0 = pw4[kn * 96 + tid];
            wv1 = pw4[kn * 96 + tid + 512];
            wv2 = pw4[kn * 96 + tid + 1024];
        }
#pragma unroll 4
        for (int kk = 0; kk < BKP; ++kk) {
            float a[8];
            *(float4*)&a[0] = *(const float4*)&As[kk * 68 + rg * 8];
            *(float4*)&a[4] = *(const float4*)&As[kk * 68 + rg * 8 + 4];
            float w[6];
#pragma unroll
            for (int j = 0; j < 6; ++j) w[j] = Ws[kk * DM + cg + 64 * j];
#pragma unroll
            for (int r = 0; r < 8; ++r)
#pragma unroll
                for (int j = 0; j < 6; ++j) acc[r][j] += a[r] * w[j];
        }
        __syncthreads();
    }

    // epilogue: +bias, LayerNorm (two-pass), write pn and pnsq.
    float gvv[6], bvv[6], pbv[6];
#pragma unroll
    for (int j = 0; j < 6; ++j) {
        pbv[j] = pb[cg + 64 * j];
        gvv[j] = lng[cg + 64 * j];
        bvv[j] = lnb[cg + 64 * j];
    }
#pragma unroll
    for (int r = 0; r < 8; ++r) {
        float vloc[6];
        float s = 0.f;
#pragma unroll
        for (int j = 0; j < 6; ++j) { vloc[j] = acc[r][j] + pbv[j]; s += vloc[j]; }
#pragma unroll
        for (int off = 32; off >= 1; off >>= 1) s += __shfl_xor(s, off);
        float mu = s * (1.0f / DM);
        float q = 0.f;
#pragma unroll
        for (int j = 0; j < 6; ++j) { float dd = vloc[j] - mu; q += dd * dd; }
#pragma unroll
        for (int off = 32; off >= 1; off >>= 1) q += __shfl_xor(q, off);
        float rstd = rsqrtf(q * (1.0f / DM) + 1e-5f);
        float ov[6];
        float ssq = 0.f;
#pragma unroll
        for (int j = 0; j < 6; ++j) {
            float p = (vloc[j] - mu) * rstd * gvv[j] + bvv[j];
            ov[j] = p; ssq += p * p;
        }
#pragma unroll
        for (int off = 32; off >= 1; off >>= 1) ssq += __shfl_xor(ssq, off);
        int mr = m0 + rg * 8 + r;
        float* dst = pn + (size_t)mr * DM + cg;
#pragma unroll
        for (int j = 0; j < 6; ++j) dst[64 * j] = ov[j];
        if (cg == 0) pnsq[mr] = ssq;
    }
}

// ---------------------------------------------------------------------------
// K2 (fused): whole k-means in ONE kernel. One block per batch, 1024 threads.
// v3: same structure as v2 but __launch_bounds__(1024, 4) -> VGPR cap 128
// (v2's default budget was 64 VGPR targeting a useless 2nd block/CU at
// grid=128, spilling acc[] to scratch: WRITE_SIZE 3MB->720MB. 1 block/CU
// is all we can use; give it the registers.)
//   assign: fully unrolled d-loop with explicit 2-ahead register prefetch.
//   update: rank-based per-cluster list build + 4-way unrolled summation
//           (independent loads; ascending order, bit-identical).
// ---------------------------------------------------------------------------
#define RED8(v) { v += __shfl_xor(v, 1); v += __shfl_xor(v, 2); \
                  v += __shfl_xor(v, 4); }

__global__ __launch_bounds__(1024, 4) void kmeans_fused_kernel(
        const float* __restrict__ pn, const float* __restrict__ pnsq,
        const float* __restrict__ pos, float* __restrict__ c0) {
    __shared__ float cs[KCL * DM];   // 24576 B, centers
    __shared__ float cq[KCL];        // |c|^2
    __shared__ float spq[NPTS];      // |p|^2
    __shared__ int   asn[256];       // assignments (196..255 = -1)
    __shared__ int   lst[KCL * 200]; // per-cluster point lists
    const int b = blockIdx.x, tid = threadIdx.x;
    const float4* pn4 = (const float4*)(pn + (size_t)b * NPTS * DM);
    float4* cs4 = (float4*)cs;

    // init: centers = pn[13k]; stage |p|^2; poison asn tail
    for (int idx = tid; idx < KCL * DM / 4; idx += 1024) {
        int k = idx / 96, d4 = idx - k * 96;
        cs4[idx] = pn4[(size_t)(13 * k) * 96 + d4];
    }
    if (tid < NPTS) spq[tid] = pnsq[b * NPTS + tid];
    if (tid >= NPTS && tid < 256) asn[tid] = -1;
    __syncthreads();
    {   // initial csq: wave w reduces |cs[w]|^2
        const int w = tid >> 6, lane = tid & 63;
        float4 A = cs4[w * 96 + lane];
        float ss = A.x * A.x + A.y * A.y + A.z * A.z + A.w * A.w;
        if (lane < 32) {
            float4 B = cs4[w * 96 + 64 + lane];
            ss += B.x * B.x + B.y * B.y + B.z * B.z + B.w * B.w;
        }
#pragma unroll
        for (int off = 32; off >= 1; off >>= 1) ss += __shfl_xor(ss, off);
        if (lane == 0) cq[w] = ss;
    }

    const int p = tid >> 3, sub = tid & 7;
    const int p2 = p + 128;
    const bool v2 = (p2 < NPTS);
    const int p2c = v2 ? p2 : 0;     // clamped (harmless redundant compute)
    for (int it = 0; it < NITER; ++it) {
        __syncthreads();   // cs/cq ready
        // ---- assign (2-ahead register prefetch) ----
        float acc0[KCL], acc1[KCL];
#pragma unroll
        for (int k = 0; k < KCL; ++k) { acc0[k] = 0.f; acc1[k] = 0.f; }
        float4 a0c = pn4[(size_t)p * 96 + sub];
        float4 a1c = pn4[(size_t)p2c * 96 + sub];
        float4 a0n = pn4[(size_t)p * 96 + sub + 8];
        float4 a1n = pn4[(size_t)p2c * 96 + sub + 8];
#pragma unroll
        for (int i = 0; i < 12; ++i) {
            float4 a0f = a0c, a1f = a1c;
            if (i + 2 < 12) {
                a0f = pn4[(size_t)p * 96 + sub + 8 * (i + 2)];
                a1f = pn4[(size_t)p2c * 96 + sub + 8 * (i + 2)];
            }
            const int d4 = sub + 8 * i;
#pragma unroll
            for (int k = 0; k < KCL; ++k) {
                float4 c = *(const float4*)&cs[k * DM + d4 * 4];
                acc0[k] += a0c.x * c.x + a0c.y * c.y + a0c.z * c.z + a0c.w * c.w;
                acc1[k] += a1c.x * c.x + a1c.y * c.y + a1c.z * c.z + a1c.w * c.w;
            }
            a0c = a0n; a1c = a1n; a0n = a0f; a1n = a1f;
        }
#pragma unroll
        for (int k = 0; k < KCL; ++k) {
            float a = acc0[k]; RED8(a); acc0[k] = a;
            float d = acc1[k]; RED8(d); acc1[k] = d;
        }
        if (sub == 0) {
            {
                float mp = spq[p];
                float best = (mp - 2.0f * acc0[0]) + cq[0]; int bk = 0;
#pragma unroll
                for (int k = 1; k < KCL; ++k) {
                    float v = (mp - 2.0f * acc0[k]) + cq[k];
                    if (v < best) { best = v; bk = k; }
                }
                asn[p] = bk;
            }
            if (v2) {
                float mp = spq[p2];
                float best = (mp - 2.0f * acc1[0]) + cq[0]; int bk = 0;
#pragma unroll
                for (int k = 1; k < KCL; ++k) {
                    float v = (mp - 2.0f * acc1[k]) + cq[k];
                    if (v < best) { best = v; bk = k; }
                }
                asn[p2] = bk;
            }
        }
        __syncthreads();   // asn ready
        // ---- update: wave w owns cluster w ----
        {
            const int w = tid >> 6, lane = tid & 63;
            // build compact ascending list for cluster w (parallel rank write)
            int cnt = 0;
#pragma unroll
            for (int ch = 0; ch < 4; ++ch) {
                int a = asn[ch * 64 + lane];
                unsigned long long mm = __ballot(a == w);
                if (a == w) {
                    int r = __popcll(mm & ((1ull << lane) - 1ull));
                    lst[w * 200 + cnt + r] = ch * 64 + lane;
                }
                cnt += __popcll(mm);
            }
            float4 sA = make_float4(0.f, 0.f, 0.f, 0.f);
            float4 sB = make_float4(0.f, 0.f, 0.f, 0.f);
            int i = 0;
            for (; i + 4 <= cnt; i += 4) {
                int n0 = lst[w * 200 + i];
                int n1 = lst[w * 200 + i + 1];
                int n2 = lst[w * 200 + i + 2];
                int n3 = lst[w * 200 + i + 3];
                float4 vA0 = pn4[(size_t)n0 * 96 + lane];
                float4 vA1 = pn4[(size_t)n1 * 96 + lane];
                float4 vA2 = pn4[(size_t)n2 * 96 + lane];
                float4 vA3 = pn4[(size_t)n3 * 96 + lane];
                float4 vB0, vB1, vB2, vB3;
                if (lane < 32) {
                    vB0 = pn4[(size_t)n0 * 96 + 64 + lane];
                    vB1 = pn4[(size_t)n1 * 96 + 64 + lane];
                    vB2 = pn4[(size_t)n2 * 96 + 64 + lane];
                    vB3 = pn4[(size_t)n3 * 96 + 64 + lane];
                }
                sA.x += vA0.x; sA.y += vA0.y; sA.z += vA0.z; sA.w += vA0.w;
                sA.x += vA1.x; sA.y += vA1.y; sA.z += vA1.z; sA.w += vA1.w;
                sA.x += vA2.x; sA.y += vA2.y; sA.z += vA2.z; sA.w += vA2.w;
                sA.x += vA3.x; sA.y += vA3.y; sA.z += vA3.z; sA.w += vA3.w;
                if (lane < 32) {
                    sB.x += vB0.x; sB.y += vB0.y; sB.z += vB0.z; sB.w += vB0.w;
                    sB.x += vB1.x; sB.y += vB1.y; sB.z += vB1.z; sB.w += vB1.w;
                    sB.x += vB2.x; sB.y += vB2.y; sB.z += vB2.z; sB.w += vB2.w;
                    sB.x += vB3.x; sB.y += vB3.y; sB.z += vB3.z; sB.w += vB3.w;
                }
            }
            for (; i < cnt; ++i) {
                int nn = lst[w * 200 + i];
                float4 vA = pn4[(size_t)nn * 96 + lane];
                sA.x += vA.x; sA.y += vA.y; sA.z += vA.z; sA.w += vA.w;
                if (lane < 32) {
                    float4 vB = pn4[(size_t)nn * 96 + 64 + lane];
                    sB.x += vB.x; sB.y += vB.y; sB.z += vB.z; sB.w += vB.w;
                }
            }
            float4 nA, nB = make_float4(0.f, 0.f, 0.f, 0.f);
            if (cnt > 0) {
                float inv = 1.0f / (float)cnt;
                nA.x = sA.x * inv; nA.y = sA.y * inv; nA.z = sA.z * inv; nA.w = sA.w * inv;
                if (lane < 32) {
                    nB.x = sB.x * inv; nB.y = sB.y * inv; nB.z = sB.z * inv; nB.w = sB.w * inv;
                }
            } else {
                nA = cs4[w * 96 + lane];
                if (lane < 32) nB = cs4[w * 96 + 64 + lane];
            }
            cs4[w * 96 + lane] = nA;
            if (lane < 32) cs4[w * 96 + 64 + lane] = nB;
            float ss = nA.x * nA.x + nA.y * nA.y + nA.z * nA.z + nA.w * nA.w
                     + nB.x * nB.x + nB.y * nB.y + nB.z * nB.z + nB.w * nB.w;
#pragma unroll
            for (int off = 32; off >= 1; off >>= 1) ss += __shfl_xor(ss, off);
            if (lane == 0) cq[w] = ss;
        }
    }
    __syncthreads();
    // finalize: c0 = cs + pos
    const float4* pos4 = (const float4*)pos;
    float4* c0b = (float4*)(c0 + (size_t)b * KCL * DM);
    for (int idx = tid; idx < KCL * DM / 4; idx += 1024) {
        float4 cv = cs4[idx];
        float4 pv = pos4[idx];
        cv.x += pv.x; cv.y += pv.y; cv.z += pv.z; cv.w += pv.w;
        c0b[idx] = cv;
    }
}

// ---------------------------------------------------------------------------
// K3: fused QKV GEMM: 3 outputs from one A-tile staging. BM=32, BN=128, BK=32.
// ---------------------------------------------------------------------------
__global__ __launch_bounds__(256) void gemm_qkv_kernel(
        const float* __restrict__ A,
        const float* __restrict__ qw, const float* __restrict__ kw,
        const float* __restrict__ vw,
        const float* __restrict__ qb, const float* __restrict__ kb,
        const float* __restrict__ vb,
        float* __restrict__ Q, float* __restrict__ K, float* __restrict__ V) {
    __shared__ float As[32 * 32];
    __shared__ float Ws[3][32 * 128];
    const int n0 = blockIdx.x * 128;
    const int m0 = blockIdx.y * 32;
    const int tid = threadIdx.x;
    const int rg = tid >> 5, cg = tid & 31;
    const int arow = tid >> 3, akg = tid & 7;
    const float* W[3] = {qw, kw, vw};

    float acc[3][4][4];
#pragma unroll
    for (int g = 0; g < 3; ++g)
#pragma unroll
        for (int r = 0; r < 4; ++r)
#pragma unroll
            for (int j = 0; j < 4; ++j) acc[g][r][j] = 0.f;

    for (int kc = 0; kc < DM; kc += 32) {
        float4 av = *(const float4*)(A + (size_t)(m0 + arow) * DM + kc + akg * 4);
        As[(akg * 4 + 0) * 32 + arow] = av.x;
        As[(akg * 4 + 1) * 32 + arow] = av.y;
        As[(akg * 4 + 2) * 32 + arow] = av.z;
        As[(akg * 4 + 3) * 32 + arow] = av.w;
#pragma unroll
        for (int g = 0; g < 3; ++g)
#pragma unroll
            for (int t = 0; t < 4; ++t) {
                int s = tid + t * 256;
                int kk = s >> 5, c4i = s & 31;
                *(float4*)&Ws[g][kk * 128 + c4i * 4] =
                    *(const float4*)(W[g] + (size_t)(kc + kk) * DM + n0 + c4i * 4);
            }
        __syncthreads();
#pragma unroll 8
        for (int kk = 0; kk < 32; ++kk) {
            float4 a = *(const float4*)&As[kk * 32 + rg * 4];
            float ar[4] = {a.x, a.y, a.z, a.w};
#pragma unroll
            for (int g = 0; g < 3; ++g) {
                float4 w = *(const float4*)&Ws[g][kk * 128 + cg * 4];
                float wr[4] = {w.x, w.y, w.z, w.w};
#pragma unroll
                for (int r = 0; r < 4; ++r)
#pragma unroll
                    for (int j = 0; j < 4; ++j) acc[g][r][j] += ar[r] * wr[j];
            }
        }
        __syncthreads();
    }
    const float* B[3] = {qb, kb, vb};
    float* O[3] = {Q, K, V};
#pragma unroll
    for (int g = 0; g < 3; ++g) {
        float4 bv = *(const float4*)(B[g] + n0 + cg * 4);
        float bvr[4] = {bv.x, bv.y, bv.z, bv.w};
#pragma unroll
        for (int r = 0; r < 4; ++r) {
            float o[4];
#pragma unroll
            for (int j = 0; j < 4; ++j) o[j] = acc[g][r][j] + bvr[j];
            *(float4*)(O[g] + (size_t)(m0 + rg * 4 + r) * DM + n0 + cg * 4) =
                *(float4*)&o[0];
        }
    }
}

// ---------------------------------------------------------------------------
// Generic fp32 GEMM: out(MxN) = A(MxK) @ W(KxN) + bias, optional exact GELU.
// ---------------------------------------------------------------------------
template <int ACT>
__global__ __launch_bounds__(256) void gemm_kernel(
        const float* __restrict__ A, const float* __restrict__ W,
        const float* __restrict__ bias, float* __restrict__ out,
        int M, int N, int Kd) {
    __shared__ float As[32 * 32];
    __shared__ float Ws[32 * 128];
    const int n0 = blockIdx.x * 128;
    const int m0 = blockIdx.y * 32;
    const int tid = threadIdx.x;
    const int rg = tid >> 5, cg = tid & 31;
    const int arow = tid >> 3, akg = tid & 7;
    float acc[4][4];
#pragma unroll
    for (int r = 0; r < 4; ++r)
#pragma unroll
        for (int j = 0; j < 4; ++j) acc[r][j] = 0.f;

    for (int kc = 0; kc < Kd; kc += 32) {
        float4 av = *(const float4*)(A + (size_t)(m0 + arow) * Kd + kc + akg * 4);
        As[(akg * 4 + 0) * 32 + arow] = av.x;
        As[(akg * 4 + 1) * 32 + arow] = av.y;
        As[(akg * 4 + 2) * 32 + arow] = av.z;
        As[(akg * 4 + 3) * 32 + arow] = av.w;
#pragma unroll
        for (int t = 0; t < 4; ++t) {
            int s = tid + t * 256;
            int kk = s >> 5, c4i = s & 31;
            *(float4*)&Ws[kk * 128 + c4i * 4] =
                *(const float4*)(W + (size_t)(kc + kk) * N + n0 + c4i * 4);
        }
        __syncthreads();
#pragma unroll 16
        for (int kk = 0; kk < 32; ++kk) {
            float4 a = *(const float4*)&As[kk * 32 + rg * 4];
            float4 w = *(const float4*)&Ws[kk * 128 + cg * 4];
            float ar[4] = {a.x, a.y, a.z, a.w};
            float wr[4] = {w.x, w.y, w.z, w.w};
#pragma unroll
            for (int r = 0; r < 4; ++r)
#pragma unroll
                for (int j = 0; j < 4; ++j) acc[r][j] += ar[r] * wr[j];
        }
        __syncthreads();
    }
    float4 bv = *(const float4*)(bias + n0 + cg * 4);
    float bvr[4] = {bv.x, bv.y, bv.z, bv.w};
#pragma unroll
    for (int r = 0; r < 4; ++r) {
        float o[4];
#pragma unroll
        for (int j = 0; j < 4; ++j) {
            float v = acc[r][j] + bvr[j];
            if (ACT == 1) v = 0.5f * v * (1.0f + erff(v * 0.70710678118654752440f));
            o[j] = v;
        }
        *(float4*)(out + (size_t)(m0 + rg * 4 + r) * N + n0 + cg * 4) = *(float4*)&o[0];
    }
}

// ---------------------------------------------------------------------------
// K4: attention + expert softmax + spectral (L @ clusters). Block = 1 batch.
// ---------------------------------------------------------------------------
__global__ __launch_bounds__(256) void attn_spectral_kernel(
        const float* __restrict__ Qg, const float* __restrict__ Kg,
        const float* __restrict__ Vg, const float* __restrict__ ew,
        const float* __restrict__ eb, float* __restrict__ c2) {
    __shared__ float Qs[KCL * 388];   // Q, later C1
    __shared__ float Ks[KCL * 388];   // K, later V
    __shared__ float ewt[NEXP * 388]; // ew transposed [e][d]
    __shared__ float Ss[KCL * 17];
    __shared__ float hws[KCL * 9];
    __shared__ float rds[NEXP];
    __shared__ float Ls[NEXP * NEXP];
    const int b = blockIdx.x, tid = threadIdx.x;
    for (int idx = tid; idx < KCL * DM; idx += 256) {
        int i = idx / DM, d = idx - i * DM;
        size_t g = (size_t)b * KCL * DM + idx;
        Qs[i * 388 + d] = Qg[g];
        Ks[i * 388 + d] = Kg[g];
    }
    for (int idx = tid; idx < DM * NEXP; idx += 256) {
        int d = idx >> 3, e = idx & 7;
        ewt[e * 388 + d] = ew[idx];
    }
    __syncthreads();
    {   // S = Q K^T / sqrt(D), softmax rows
        int i = tid >> 4, j = tid & 15;
        float acc = 0.f;
        for (int d = 0; d < DM; d += 4) {
            float4 q = *(const float4*)&Qs[i * 388 + d];
            float4 k = *(const float4*)&Ks[j * 388 + d];
            acc += q.x * k.x + q.y * k.y + q.z * k.z + q.w * k.w;
        }
        float s = acc / sqrtf((float)DM);
        float mx = s;
#pragma unroll
        for (int off = 8; off >= 1; off >>= 1) mx = fmaxf(mx, __shfl_xor(mx, off));
        float p = expf(s - mx);
        float sm = p;
#pragma unroll
        for (int off = 8; off >= 1; off >>= 1) sm += __shfl_xor(sm, off);
        Ss[i * 17 + j] = p / sm;
    }
    __syncthreads();
    for (int idx = tid; idx < KCL * DM; idx += 256) {
        int i = idx / DM, d = idx - i * DM;
        Ks[i * 388 + d] = Vg[(size_t)b * KCL * DM + idx];
    }
    __syncthreads();
    for (int idx = tid; idx < KCL * DM; idx += 256) {
        int i = idx / DM, d = idx - i * DM;
        float acc = 0.f;
#pragma unroll
        for (int j = 0; j < KCL; ++j) acc += Ss[i * 17 + j] * Ks[j * 388 + d];
        Qs[i * 388 + d] = acc;
    }
    __syncthreads();
    if (tid < 128) {
        int e = tid >> 4, i = tid & 15;
        float l = 0.f;
        for (int d4 = 0; d4 < DM / 4; ++d4) {
            float4 q = *(const float4*)&Qs[i * 388 + d4 * 4];
            float4 w = *(const float4*)&ewt[e * 388 + d4 * 4];
            l += q.x * w.x + q.y * w.y + q.z * w.z + q.w * w.w;
        }
        l += eb[e];
        float mx = l;
#pragma unroll
        for (int off = 8; off >= 1; off >>= 1) mx = fmaxf(mx, __shfl_xor(mx, off));
        float p = expf(l - mx);
        float sm = p;
#pragma unroll
        for (int off = 8; off >= 1; off >>= 1) sm += __shfl_xor(sm, off);
        float h = p / sm;
        hws[i * 9 + e] = h;
        float sd = h;
#pragma unroll
        for (int off = 8; off >= 1; off >>= 1) sd += __shfl_xor(sd, off);
        if (i == 0) rds[e] = 1.0f / sqrtf(sd);
    }
    __syncthreads();
    if (tid < 64) {
        int e = tid >> 3, f = tid & 7;
        float gsum = 0.f;
#pragma unroll
        for (int k = 0; k < KCL; ++k) gsum += hws[k * 9 + e] * hws[k * 9 + f];
        Ls[e * 8 + f] = ((e == f) ? 1.0f : 0.0f) - rds[e] * gsum;
    }
    __syncthreads();
    for (int idx = tid; idx < KCL * DM; idx += 256) {
        int i = idx / DM, d = idx - i * DM;
        float acc = 0.f;
        if (i < NEXP) {
#pragma unroll
            for (int j = 0; j < NEXP; ++j) acc += Ls[i * 8 + j] * Qs[j * 388 + d];
        }
        c2[(size_t)b * KCL * DM + idx] = acc;
    }
}

// ---------------------------------------------------------------------------
// K6: normalize rows, sim = nc @ nc^T, OR (sim>0.9) into global mask
// ---------------------------------------------------------------------------
__global__ __launch_bounds__(256) void simmask_kernel(const float* __restrict__ c4,
                                                      int* __restrict__ mask) {
    __shared__ float Cs[KCL * 388];
    __shared__ float rns[KCL];
    const int b = blockIdx.x, tid = threadIdx.x;
    for (int idx = tid; idx < KCL * DM; idx += 256) {
        int i = idx / DM, d = idx - i * DM;
        Cs[i * 388 + d] = c4[(size_t)b * KCL * DM + idx];
    }
    __syncthreads();
    {
        int i = tid >> 4, s = tid & 15;
        float ss = 0.f;
        for (int t = 0; t < 24; ++t) { float v = Cs[i * 388 + s + 16 * t]; ss += v * v; }
#pragma unroll
        for (int off = 8; off >= 1; off >>= 1) ss += __shfl_xor(ss, off);
        if (s == 0) rns[i] = 1.0f / fmaxf(sqrtf(ss), 1e-12f);
    }
    __syncthreads();
    for (int idx = tid; idx < KCL * DM; idx += 256) {
        int i = idx / DM, d = idx - i * DM;
        Cs[i * 388 + d] *= rns[i];
    }
    __syncthreads();
    {
        int i = tid >> 4, j = tid & 15;
        if (j > i) {
            float dp = 0.f;
            for (int d = 0; d < DM; d += 4) {
                float4 a = *(const float4*)&Cs[i * 388 + d];
                float4 c = *(const float4*)&Cs[j * 388 + d];
                dp += a.x * c.x + a.y * c.y + a.z * c.z + a.w * c.w;
            }
            if (dp > 0.9f) atomicOr(&mask[i * KCL + j], 1);
        }
    }
}

// ---------------------------------------------------------------------------
// K7: sequential pairwise merge + mean + feedback gate -> c5
// ---------------------------------------------------------------------------
__global__ __launch_bounds__(256) void merge_fb_kernel(
        const float* __restrict__ c4, const int* __restrict__ mask,
        const float* __restrict__ fbw, const float* __restrict__ fbb,
        const float* __restrict__ fgw, const float* __restrict__ fgb,
        float* __restrict__ c5) {
    __shared__ int   mk[256];
    __shared__ float gs[DM];
    __shared__ float wred[3];
    __shared__ float gatev;
    const int b = blockIdx.x, tid = threadIdx.x;
    mk[tid] = mask[tid];
    const bool act = tid < 192;
    const int t = tid;
    float2 v[KCL];
    if (act) {
#pragma unroll
        for (int i = 0; i < KCL; ++i)
            v[i] = *(const float2*)(c4 + (size_t)b * KCL * DM + i * DM + 2 * t);
    }
    __syncthreads();
    if (act) {
#pragma unroll
        for (int i = 0; i < KCL; ++i)
#pragma unroll
            for (int j = i + 1; j < KCL; ++j)
                if (mk[i * KCL + j]) {
                    float mx = 0.5f * (v[i].x + v[j].x);
                    float my = 0.5f * (v[i].y + v[j].y);
                    v[i].x = mx; v[i].y = my; v[j].x = mx; v[j].y = my;
                }
    }
    float2 gv = {0.f, 0.f};
    if (act) {
#pragma unroll
        for (int i = 0; i < KCL; ++i) { gv.x += v[i].x; gv.y += v[i].y; }
        gv.x *= 0.0625f; gv.y *= 0.0625f;
        gs[2 * t] = gv.x; gs[2 * t + 1] = gv.y;
    }
    float pg = act ? (gv.x * fgw[2 * t] + gv.y * fgw[2 * t + 1]) : 0.f;
#pragma unroll
    for (int off = 32; off >= 1; off >>= 1) pg += __shfl_xor(pg, off);
    if (act && (tid & 63) == 0) wred[tid >> 6] = pg;
    __syncthreads();
    if (tid == 0) {
        float d = wred[0] + wred[1] + wred[2] + fgb[0];
        gatev = 1.0f / (1.0f + expf(-d));
    }
    __syncthreads();
    if (act) {
        float fx = fbb[2 * t], fy = fbb[2 * t + 1];
        for (int j = 0; j < DM; ++j) {
            float gj = gs[j];
            const float2 w = *(const float2*)(fbw + (size_t)j * DM + 2 * t);
            fx += gj * w.x; fy += gj * w.y;
        }
        float gt = gatev;
#pragma unroll
        for (int i = 0; i < KCL; ++i) {
            float2 o = {v[i].x + fx * gt, v[i].y + fy * gt};
            *(float2*)(c5 + (size_t)b * KCL * DM + i * DM + 2 * t) = o;
        }
    }
}

// ---------------------------------------------------------------------------
// K8: classifier, split-K with fp32 atomics. out pre-initialized with cb.
// ---------------------------------------------------------------------------
__global__ __launch_bounds__(256) void cls_kernel(const float* __restrict__ A,
                                                  const float* __restrict__ Wt,
                                                  float* __restrict__ out) {
    __shared__ float As[32 * 32];
    __shared__ float Ws[32 * 128];
    const int n0 = blockIdx.x * 128;
    const int m0 = blockIdx.y * 32;
    const int k0 = blockIdx.z * 768;
    const int tid = threadIdx.x;
    const int rg = tid >> 5, cg = tid & 31;
    const int arow = tid >> 3, akg = tid & 7;
    float acc[4][4];
#pragma unroll
    for (int r = 0; r < 4; ++r)
#pragma unroll
        for (int j = 0; j < 4; ++j) acc[r][j] = 0.f;

    for (int kc = k0; kc < k0 + 768; kc += 32) {
        float4 av = *(const float4*)(A + (size_t)(m0 + arow) * (KCL * DM) + kc + akg * 4);
        As[(akg * 4 + 0) * 32 + arow] = av.x;
        As[(akg * 4 + 1) * 32 + arow] = av.y;
        As[(akg * 4 + 2) * 32 + arow] = av.z;
        As[(akg * 4 + 3) * 32 + arow] = av.w;
#pragma unroll
        for (int ti = 0; ti < 4; ++ti) {
            int s = tid + ti * 256;
            int kk = s >> 5, c4i = s & 31;
            int col = n0 + c4i * 4;
            float4 wv = make_float4(0.f, 0.f, 0.f, 0.f);
            if (col < NCLS) wv = *(const float4*)(Wt + (size_t)(kc + kk) * NCLS + col);
            *(float4*)&Ws[kk * 128 + c4i * 4] = wv;
        }
        __syncthreads();
#pragma unroll 16
        for (int kk = 0; kk < 32; ++kk) {
            float4 a = *(const float4*)&As[kk * 32 + rg * 4];
            float4 w = *(const float4*)&Ws[kk * 128 + cg * 4];
            float ar[4] = {a.x, a.y, a.z, a.w};
            float wr[4] = {w.x, w.y, w.z, w.w};
#pragma unroll
            for (int r = 0; r < 4; ++r)
#pragma unroll
                for (int j = 0; j < 4; ++j) acc[r][j] += ar[r] * wr[j];
        }
        __syncthreads();
    }
    int col = n0 + cg * 4;
    if (col < NCLS) {
#pragma unroll
        for (int r = 0; r < 4; ++r) {
            int row = m0 + rg * 4 + r;
#pragma unroll
            for (int j = 0; j < 4; ++j)
                atomicAdd(&out[(size_t)row * NCLS + col + j], acc[r][j]);
        }
    }
}

// ---------------------------------------------------------------------------
extern "C" void kernel_launch(void* const* d_in, const int* in_sizes, int n_in,
                              void* d_out, int out_size, void* d_ws, size_t ws_size,
                              hipStream_t stream) {
    const float* x   = (const float*)d_in[0];
    const float* pw  = (const float*)d_in[1];
    const float* pb  = (const float*)d_in[2];
    const float* lng = (const float*)d_in[3];
    const float* lnb = (const float*)d_in[4];
    const float* pos = (const float*)d_in[5];
    const float* qw  = (const float*)d_in[6];
    const float* qb  = (const float*)d_in[7];
    const float* kw  = (const float*)d_in[8];
    const float* kb  = (const float*)d_in[9];
    const float* vw  = (const float*)d_in[10];
    const float* vb  = (const float*)d_in[11];
    const float* ew  = (const float*)d_in[12];
    const float* eb  = (const float*)d_in[13];
    const float* nw  = (const float*)d_in[14];
    const float* nb  = (const float*)d_in[15];
    const float* m1w = (const float*)d_in[16];
    const float* m1b = (const float*)d_in[17];
    const float* m2w = (const float*)d_in[18];
    const float* m2b = (const float*)d_in[19];
    const float* fbw = (const float*)d_in[20];
    const float* fbb = (const float*)d_in[21];
    const float* fgw = (const float*)d_in[22];
    const float* fgb = (const float*)d_in[23];
    const float* cw  = (const float*)d_in[24];
    const float* cb  = (const float*)d_in[25];
    float* out = (float*)d_out;
    float* ws  = (float*)d_ws;

    // workspace layout (floats)
    float* pn_   = ws;                    // 128*196*384 = 9,633,792
    float* pnsq_ = ws + 9633792;          // 25,088
    float* c0_   = ws + 9658880;          // 786,432 (clusters0; later c5)
    float* Q_    = ws + 10445312;         // 786,432 (later c3)
    float* K_    = ws + 11231744;         // 786,432 (later h)
    float* V_    = ws + 12018176;         // 786,432 (later c4)
    float* c2_   = ws + 12804608;         // 786,432
    int*   mask_ = (int*)(ws + 13591040); // 256 ints
    float* c3_ = Q_;
    float* h_  = K_;
    float* c4_ = V_;
    float* c5_ = c0_;

    init_kernel<<<501, 256, 0, stream>>>(cb, out, mask_);
    patch_ln_kernel<<<392, 512, 0, stream>>>(x, pw, pb, lng, lnb, pn_, pnsq_);

    kmeans_fused_kernel<<<NBATCH, 1024, 0, stream>>>(pn_, pnsq_, pos, c0_);

    gemm_qkv_kernel<<<dim3(3, 64), 256, 0, stream>>>(c0_, qw, kw, vw, qb, kb, vb,
                                                     Q_, K_, V_);
    attn_spectral_kernel<<<NBATCH, 256, 0, stream>>>(Q_, K_, V_, ew, eb, c2_);
    gemm_kernel<0><<<dim3(3, 64), 256, 0, stream>>>(c2_, nw, nb, c3_, 2048, DM, DM);
    gemm_kernel<1><<<dim3(3, 64), 256, 0, stream>>>(c3_, m1w, m1b, h_, 2048, DM, DM);
    gemm_kernel<0><<<dim3(3, 64), 256, 0, stream>>>(h_, m2w, m2b, c4_, 2048, DM, DM);
    simmask_kernel<<<NBATCH, 256, 0, stream>>>(c4_, mask_);
    merge_fb_kernel<<<NBATCH, 256, 0, stream>>>(c4_, mask_, fbw, fbb, fgw, fgb, c5_);
    cls_kernel<<<dim3(8, 4, 8), 256, 0, stream>>>(c5_, cw, out);
}

// Round 5
// 914.985 us; speedup vs baseline: 1.4412x; 1.4412x over previous
//
#include <hip/hip_runtime.h>
#include <math.h>

// Shapes (fixed by the problem)
#define NBATCH 128
#define NPTS   196     // 14*14 patches
#define DIN    768     // 3*16*16
#define DM     384
#define KCL    16
#define NEXP   8
#define NITER  10
#define NCLS   1000

// ---------------------------------------------------------------------------
// K0: init out = cb (classifier bias), zero the merge mask
// ---------------------------------------------------------------------------
__global__ __launch_bounds__(256) void init_kernel(const float* __restrict__ cb,
                                                   float* __restrict__ out,
                                                   int* __restrict__ mask) {
    int idx = blockIdx.x * 256 + threadIdx.x;
    if (idx < NBATCH * NCLS) {
        out[idx] = cb[idx % NCLS];
    } else if (idx < NBATCH * NCLS + 256) {
        mask[idx - NBATCH * NCLS] = 0;
    }
}

// ---------------------------------------------------------------------------
// K1: patch extraction + GEMM (25088x768 @ 768x384) + bias + LayerNorm + pnsq
// 512 threads, BM=64, BK=16, micro 8x6. v2: register double-buffered staging
// (prefetch tile kc+16 into regs right after barrier; LDS-write next iter).
// ---------------------------------------------------------------------------
#define BKP 16
__global__ __launch_bounds__(512, 4) void patch_ln_kernel(
        const float* __restrict__ x, const float* __restrict__ pw,
        const float* __restrict__ pb, const float* __restrict__ lng,
        const float* __restrict__ lnb, float* __restrict__ pn,
        float* __restrict__ pnsq) {
    __shared__ float As[BKP * 68];   // [kk][row], 64 rows + 4 pad
    __shared__ float Ws[BKP * DM];   // [kk][col]
    const int tid = threadIdx.x;
    const int m0  = blockIdx.x * 64;
    const int rg  = tid >> 6;        // 8 row-groups of 8 rows (one wave each)
    const int cg  = tid & 63;        // 64 col-groups; cols cg + 64j
    // A-stage mapping (first 256 threads): 64 loader rows x 4 k-quads
    const int lr = (tid & 255) >> 2, kq = tid & 3;
    const int m  = m0 + lr;
    const int bi = m / NPTS, n = m - bi * NPTS;
    const int nh = n / 14, nwp = n - nh * 14;
    const float* xb = x + (size_t)bi * 150528 + (size_t)(nh * 16) * 224 + nwp * 16;

    float acc[8][6];
#pragma unroll
    for (int r = 0; r < 8; ++r)
#pragma unroll
        for (int j = 0; j < 6; ++j) acc[r][j] = 0.f;

    const float4* pw4 = (const float4*)pw;
    // prefetch tile 0 into regs
    float4 xv = make_float4(0.f, 0.f, 0.f, 0.f);
    float4 wv0, wv1, wv2;
    if (tid < 256) {
        int k = kq * 4;
        int c = k >> 8, py = (k >> 4) & 15, px = k & 15;
        xv = *(const float4*)(xb + c * 50176 + py * 224 + px);
    }
    wv0 = pw4[tid];
    wv1 = pw4[tid + 512];
    wv2 = pw4[tid + 1024];

    for (int kc = 0; kc < DIN; kc += BKP) {
        // commit prefetched regs to LDS
        if (tid < 256) {
            As[(kq * 4 + 0) * 68 + lr] = xv.x;
            As[(kq * 4 + 1) * 68 + lr] = xv.y;
            As[(kq * 4 + 2) * 68 + lr] = xv.z;
            As[(kq * 4 + 3) * 68 + lr] = xv.w;
        }
        ((float4*)Ws)[tid]        = wv0;
        ((float4*)Ws)[tid + 512]  = wv1;
        ((float4*)Ws)[tid + 1024] = wv2;
        __syncthreads();
        // prefetch next tile (overlaps with compute below)
        const int kn = kc + BKP;
        if (kn < DIN) {
            if (tid < 256) {
                int k = kn + kq * 4;
                int c = k >> 8, py = (k >> 4) & 15, px = k & 15;
                xv = *(const float4*)(xb + c * 50176 + py * 224 + px);
            }
            wv0 = pw4[kn * 96 + tid];
            wv1 = pw4[kn * 96 + tid + 512];
            wv2 = pw4[kn * 96 + tid + 1024];
        }
#pragma unroll 4
        for (int kk = 0; kk < BKP; ++kk) {
            float a[8];
            *(float4*)&a[0] = *(const float4*)&As[kk * 68 + rg * 8];
            *(float4*)&a[4] = *(const float4*)&As[kk * 68 + rg * 8 + 4];
            float w[6];
#pragma unroll
            for (int j = 0; j < 6; ++j) w[j] = Ws[kk * DM + cg + 64 * j];
#pragma unroll
            for (int r = 0; r < 8; ++r)
#pragma unroll
                for (int j = 0; j < 6; ++j) acc[r][j] += a[r] * w[j];
        }
        __syncthreads();
    }

    // epilogue: +bias, LayerNorm (two-pass), write pn and pnsq.
    float gvv[6], bvv[6], pbv[6];
#pragma unroll
    for (int j = 0; j < 6; ++j) {
        pbv[j] = pb[cg + 64 * j];
        gvv[j] = lng[cg + 64 * j];
        bvv[j] = lnb[cg + 64 * j];
    }
#pragma unroll
    for (int r = 0; r < 8; ++r) {
        float vloc[6];
        float s = 0.f;
#pragma unroll
        for (int j = 0; j < 6; ++j) { vloc[j] = acc[r][j] + pbv[j]; s += vloc[j]; }
#pragma unroll
        for (int off = 32; off >= 1; off >>= 1) s += __shfl_xor(s, off);
        float mu = s * (1.0f / DM);
        float q = 0.f;
#pragma unroll
        for (int j = 0; j < 6; ++j) { float dd = vloc[j] - mu; q += dd * dd; }
#pragma unroll
        for (int off = 32; off >= 1; off >>= 1) q += __shfl_xor(q, off);
        float rstd = rsqrtf(q * (1.0f / DM) + 1e-5f);
        float ov[6];
        float ssq = 0.f;
#pragma unroll
        for (int j = 0; j < 6; ++j) {
            float p = (vloc[j] - mu) * rstd * gvv[j] + bvv[j];
            ov[j] = p; ssq += p * p;
        }
#pragma unroll
        for (int off = 32; off >= 1; off >>= 1) ssq += __shfl_xor(ssq, off);
        int mr = m0 + rg * 8 + r;
        float* dst = pn + (size_t)mr * DM + cg;
#pragma unroll
        for (int j = 0; j < 6; ++j) dst[64 * j] = ov[j];
        if (cg == 0) pnsq[mr] = ssq;
    }
}

// ---------------------------------------------------------------------------
// K2 (fused): whole k-means in ONE kernel. One block per batch, 1024 threads.
// v4: assign reverted to the round-2 no-spill form (48 VGPR, 289us measured);
// update keeps the rank-list + 4-way-unrolled summation (independent loads,
// ascending order = bit-identical). amdgpu_waves_per_eu(4,4) pins the
// compiler's occupancy target to 4 waves/EU (VGPR budget 128) — prevents
// the 64-VGPR heuristic that spilled acc[] in v2/v3 (WRITE_SIZE 720MB).
// ---------------------------------------------------------------------------
#define RED8(v) { v += __shfl_xor(v, 1); v += __shfl_xor(v, 2); \
                  v += __shfl_xor(v, 4); }

__global__ __launch_bounds__(1024)
__attribute__((amdgpu_waves_per_eu(4, 4)))
void kmeans_fused_kernel(
        const float* __restrict__ pn, const float* __restrict__ pnsq,
        const float* __restrict__ pos, float* __restrict__ c0) {
    __shared__ float cs[KCL * DM];   // 24576 B, centers
    __shared__ float cq[KCL];        // |c|^2
    __shared__ float spq[NPTS];      // |p|^2
    __shared__ int   asn[256];       // assignments (196..255 = -1)
    __shared__ int   lst[KCL * 200]; // per-cluster point lists
    const int b = blockIdx.x, tid = threadIdx.x;
    const float4* pn4 = (const float4*)(pn + (size_t)b * NPTS * DM);
    float4* cs4 = (float4*)cs;

    // init: centers = pn[13k]; stage |p|^2; poison asn tail
    for (int idx = tid; idx < KCL * DM / 4; idx += 1024) {
        int k = idx / 96, d4 = idx - k * 96;
        cs4[idx] = pn4[(size_t)(13 * k) * 96 + d4];
    }
    if (tid < NPTS) spq[tid] = pnsq[b * NPTS + tid];
    if (tid >= NPTS && tid < 256) asn[tid] = -1;
    __syncthreads();
    {   // initial csq: wave w reduces |cs[w]|^2
        const int w = tid >> 6, lane = tid & 63;
        float4 A = cs4[w * 96 + lane];
        float ss = A.x * A.x + A.y * A.y + A.z * A.z + A.w * A.w;
        if (lane < 32) {
            float4 B = cs4[w * 96 + 64 + lane];
            ss += B.x * B.x + B.y * B.y + B.z * B.z + B.w * B.w;
        }
#pragma unroll
        for (int off = 32; off >= 1; off >>= 1) ss += __shfl_xor(ss, off);
        if (lane == 0) cq[w] = ss;
    }

    const int p = tid >> 3, sub = tid & 7;
    const int p2 = p + 128;
    const bool v2 = (p2 < NPTS);
    const int p2c = v2 ? p2 : 0;     // clamped (harmless redundant compute)
    for (int it = 0; it < NITER; ++it) {
        __syncthreads();   // cs/cq ready
        // ---- assign (round-2 form: no explicit prefetch, no spill) ----
        float acc0[KCL], acc1[KCL];
#pragma unroll
        for (int k = 0; k < KCL; ++k) { acc0[k] = 0.f; acc1[k] = 0.f; }
#pragma unroll 2
        for (int i = 0; i < 12; ++i) {
            const int d4 = sub + 8 * i;
            float4 a0 = pn4[(size_t)p * 96 + d4];
            float4 a1 = pn4[(size_t)p2c * 96 + d4];
#pragma unroll
            for (int k = 0; k < KCL; ++k) {
                float4 c = *(const float4*)&cs[k * DM + d4 * 4];
                acc0[k] += a0.x * c.x + a0.y * c.y + a0.z * c.z + a0.w * c.w;
                acc1[k] += a1.x * c.x + a1.y * c.y + a1.z * c.z + a1.w * c.w;
            }
        }
#pragma unroll
        for (int k = 0; k < KCL; ++k) {
            float a = acc0[k]; RED8(a); acc0[k] = a;
            float d = acc1[k]; RED8(d); acc1[k] = d;
        }
        if (sub == 0) {
            {
                float mp = spq[p];
                float best = (mp - 2.0f * acc0[0]) + cq[0]; int bk = 0;
#pragma unroll
                for (int k = 1; k < KCL; ++k) {
                    float v = (mp - 2.0f * acc0[k]) + cq[k];
                    if (v < best) { best = v; bk = k; }
                }
                asn[p] = bk;
            }
            if (v2) {
                float mp = spq[p2];
                float best = (mp - 2.0f * acc1[0]) + cq[0]; int bk = 0;
#pragma unroll
                for (int k = 1; k < KCL; ++k) {
                    float v = (mp - 2.0f * acc1[k]) + cq[k];
                    if (v < best) { best = v; bk = k; }
                }
                asn[p2] = bk;
            }
        }
        __syncthreads();   // asn ready
        // ---- update: wave w owns cluster w ----
        {
            const int w = tid >> 6, lane = tid & 63;
            // build compact ascending list for cluster w (parallel rank write)
            int cnt = 0;
#pragma unroll
            for (int ch = 0; ch < 4; ++ch) {
                int a = asn[ch * 64 + lane];
                unsigned long long mm = __ballot(a == w);
                if (a == w) {
                    int r = __popcll(mm & ((1ull << lane) - 1ull));
                    lst[w * 200 + cnt + r] = ch * 64 + lane;
                }
                cnt += __popcll(mm);
            }
            float4 sA = make_float4(0.f, 0.f, 0.f, 0.f);
            float4 sB = make_float4(0.f, 0.f, 0.f, 0.f);
            int i = 0;
            for (; i + 4 <= cnt; i += 4) {
                int n0 = lst[w * 200 + i];
                int n1 = lst[w * 200 + i + 1];
                int n2 = lst[w * 200 + i + 2];
                int n3 = lst[w * 200 + i + 3];
                float4 vA0 = pn4[(size_t)n0 * 96 + lane];
                float4 vA1 = pn4[(size_t)n1 * 96 + lane];
                float4 vA2 = pn4[(size_t)n2 * 96 + lane];
                float4 vA3 = pn4[(size_t)n3 * 96 + lane];
                float4 vB0, vB1, vB2, vB3;
                if (lane < 32) {
                    vB0 = pn4[(size_t)n0 * 96 + 64 + lane];
                    vB1 = pn4[(size_t)n1 * 96 + 64 + lane];
                    vB2 = pn4[(size_t)n2 * 96 + 64 + lane];
                    vB3 = pn4[(size_t)n3 * 96 + 64 + lane];
                }
                sA.x += vA0.x; sA.y += vA0.y; sA.z += vA0.z; sA.w += vA0.w;
                sA.x += vA1.x; sA.y += vA1.y; sA.z += vA1.z; sA.w += vA1.w;
                sA.x += vA2.x; sA.y += vA2.y; sA.z += vA2.z; sA.w += vA2.w;
                sA.x += vA3.x; sA.y += vA3.y; sA.z += vA3.z; sA.w += vA3.w;
                if (lane < 32) {
                    sB.x += vB0.x; sB.y += vB0.y; sB.z += vB0.z; sB.w += vB0.w;
                    sB.x += vB1.x; sB.y += vB1.y; sB.z += vB1.z; sB.w += vB1.w;
                    sB.x += vB2.x; sB.y += vB2.y; sB.z += vB2.z; sB.w += vB2.w;
                    sB.x += vB3.x; sB.y += vB3.y; sB.z += vB3.z; sB.w += vB3.w;
                }
            }
            for (; i < cnt; ++i) {
                int nn = lst[w * 200 + i];
                float4 vA = pn4[(size_t)nn * 96 + lane];
                sA.x += vA.x; sA.y += vA.y; sA.z += vA.z; sA.w += vA.w;
                if (lane < 32) {
                    float4 vB = pn4[(size_t)nn * 96 + 64 + lane];
                    sB.x += vB.x; sB.y += vB.y; sB.z += vB.z; sB.w += vB.w;
                }
            }
            float4 nA, nB = make_float4(0.f, 0.f, 0.f, 0.f);
            if (cnt > 0) {
                float inv = 1.0f / (float)cnt;
                nA.x = sA.x * inv; nA.y = sA.y * inv; nA.z = sA.z * inv; nA.w = sA.w * inv;
                if (lane < 32) {
                    nB.x = sB.x * inv; nB.y = sB.y * inv; nB.z = sB.z * inv; nB.w = sB.w * inv;
                }
            } else {
                nA = cs4[w * 96 + lane];
                if (lane < 32) nB = cs4[w * 96 + 64 + lane];
            }
            cs4[w * 96 + lane] = nA;
            if (lane < 32) cs4[w * 96 + 64 + lane] = nB;
            float ss = nA.x * nA.x + nA.y * nA.y + nA.z * nA.z + nA.w * nA.w
                     + nB.x * nB.x + nB.y * nB.y + nB.z * nB.z + nB.w * nB.w;
#pragma unroll
            for (int off = 32; off >= 1; off >>= 1) ss += __shfl_xor(ss, off);
            if (lane == 0) cq[w] = ss;
        }
    }
    __syncthreads();
    // finalize: c0 = cs + pos
    const float4* pos4 = (const float4*)pos;
    float4* c0b = (float4*)(c0 + (size_t)b * KCL * DM);
    for (int idx = tid; idx < KCL * DM / 4; idx += 1024) {
        float4 cv = cs4[idx];
        float4 pv = pos4[idx];
        cv.x += pv.x; cv.y += pv.y; cv.z += pv.z; cv.w += pv.w;
        c0b[idx] = cv;
    }
}

// ---------------------------------------------------------------------------
// K3: fused QKV GEMM: 3 outputs from one A-tile staging. BM=32, BN=128, BK=32.
// ---------------------------------------------------------------------------
__global__ __launch_bounds__(256) void gemm_qkv_kernel(
        const float* __restrict__ A,
        const float* __restrict__ qw, const float* __restrict__ kw,
        const float* __restrict__ vw,
        const float* __restrict__ qb, const float* __restrict__ kb,
        const float* __restrict__ vb,
        float* __restrict__ Q, float* __restrict__ K, float* __restrict__ V) {
    __shared__ float As[32 * 32];
    __shared__ float Ws[3][32 * 128];
    const int n0 = blockIdx.x * 128;
    const int m0 = blockIdx.y * 32;
    const int tid = threadIdx.x;
    const int rg = tid >> 5, cg = tid & 31;
    const int arow = tid >> 3, akg = tid & 7;
    const float* W[3] = {qw, kw, vw};

    float acc[3][4][4];
#pragma unroll
    for (int g = 0; g < 3; ++g)
#pragma unroll
        for (int r = 0; r < 4; ++r)
#pragma unroll
            for (int j = 0; j < 4; ++j) acc[g][r][j] = 0.f;

    for (int kc = 0; kc < DM; kc += 32) {
        float4 av = *(const float4*)(A + (size_t)(m0 + arow) * DM + kc + akg * 4);
        As[(akg * 4 + 0) * 32 + arow] = av.x;
        As[(akg * 4 + 1) * 32 + arow] = av.y;
        As[(akg * 4 + 2) * 32 + arow] = av.z;
        As[(akg * 4 + 3) * 32 + arow] = av.w;
#pragma unroll
        for (int g = 0; g < 3; ++g)
#pragma unroll
            for (int t = 0; t < 4; ++t) {
                int s = tid + t * 256;
                int kk = s >> 5, c4i = s & 31;
                *(float4*)&Ws[g][kk * 128 + c4i * 4] =
                    *(const float4*)(W[g] + (size_t)(kc + kk) * DM + n0 + c4i * 4);
            }
        __syncthreads();
#pragma unroll 8
        for (int kk = 0; kk < 32; ++kk) {
            float4 a = *(const float4*)&As[kk * 32 + rg * 4];
            float ar[4] = {a.x, a.y, a.z, a.w};
#pragma unroll
            for (int g = 0; g < 3; ++g) {
                float4 w = *(const float4*)&Ws[g][kk * 128 + cg * 4];
                float wr[4] = {w.x, w.y, w.z, w.w};
#pragma unroll
                for (int r = 0; r < 4; ++r)
#pragma unroll
                    for (int j = 0; j < 4; ++j) acc[g][r][j] += ar[r] * wr[j];
            }
        }
        __syncthreads();
    }
    const float* B[3] = {qb, kb, vb};
    float* O[3] = {Q, K, V};
#pragma unroll
    for (int g = 0; g < 3; ++g) {
        float4 bv = *(const float4*)(B[g] + n0 + cg * 4);
        float bvr[4] = {bv.x, bv.y, bv.z, bv.w};
#pragma unroll
        for (int r = 0; r < 4; ++r) {
            float o[4];
#pragma unroll
            for (int j = 0; j < 4; ++j) o[j] = acc[g][r][j] + bvr[j];
            *(float4*)(O[g] + (size_t)(m0 + rg * 4 + r) * DM + n0 + cg * 4) =
                *(float4*)&o[0];
        }
    }
}

// ---------------------------------------------------------------------------
// Generic fp32 GEMM: out(MxN) = A(MxK) @ W(KxN) + bias, optional exact GELU.
// ---------------------------------------------------------------------------
template <int ACT>
__global__ __launch_bounds__(256) void gemm_kernel(
        const float* __restrict__ A, const float* __restrict__ W,
        const float* __restrict__ bias, float* __restrict__ out,
        int M, int N, int Kd) {
    __shared__ float As[32 * 32];
    __shared__ float Ws[32 * 128];
    const int n0 = blockIdx.x * 128;
    const int m0 = blockIdx.y * 32;
    const int tid = threadIdx.x;
    const int rg = tid >> 5, cg = tid & 31;
    const int arow = tid >> 3, akg = tid & 7;
    float acc[4][4];
#pragma unroll
    for (int r = 0; r < 4; ++r)
#pragma unroll
        for (int j = 0; j < 4; ++j) acc[r][j] = 0.f;

    for (int kc = 0; kc < Kd; kc += 32) {
        float4 av = *(const float4*)(A + (size_t)(m0 + arow) * Kd + kc + akg * 4);
        As[(akg * 4 + 0) * 32 + arow] = av.x;
        As[(akg * 4 + 1) * 32 + arow] = av.y;
        As[(akg * 4 + 2) * 32 + arow] = av.z;
        As[(akg * 4 + 3) * 32 + arow] = av.w;
#pragma unroll
        for (int t = 0; t < 4; ++t) {
            int s = tid + t * 256;
            int kk = s >> 5, c4i = s & 31;
            *(float4*)&Ws[kk * 128 + c4i * 4] =
                *(const float4*)(W + (size_t)(kc + kk) * N + n0 + c4i * 4);
        }
        __syncthreads();
#pragma unroll 16
        for (int kk = 0; kk < 32; ++kk) {
            float4 a = *(const float4*)&As[kk * 32 + rg * 4];
            float4 w = *(const float4*)&Ws[kk * 128 + cg * 4];
            float ar[4] = {a.x, a.y, a.z, a.w};
            float wr[4] = {w.x, w.y, w.z, w.w};
#pragma unroll
            for (int r = 0; r < 4; ++r)
#pragma unroll
                for (int j = 0; j < 4; ++j) acc[r][j] += ar[r] * wr[j];
        }
        __syncthreads();
    }
    float4 bv = *(const float4*)(bias + n0 + cg * 4);
    float bvr[4] = {bv.x, bv.y, bv.z, bv.w};
#pragma unroll
    for (int r = 0; r < 4; ++r) {
        float o[4];
#pragma unroll
        for (int j = 0; j < 4; ++j) {
            float v = acc[r][j] + bvr[j];
            if (ACT == 1) v = 0.5f * v * (1.0f + erff(v * 0.70710678118654752440f));
            o[j] = v;
        }
        *(float4*)(out + (size_t)(m0 + rg * 4 + r) * N + n0 + cg * 4) = *(float4*)&o[0];
    }
}

// ---------------------------------------------------------------------------
// K4: attention + expert softmax + spectral (L @ clusters). Block = 1 batch.
// ---------------------------------------------------------------------------
__global__ __launch_bounds__(256) void attn_spectral_kernel(
        const float* __restrict__ Qg, const float* __restrict__ Kg,
        const float* __restrict__ Vg, const float* __restrict__ ew,
        const float* __restrict__ eb, float* __restrict__ c2) {
    __shared__ float Qs[KCL * 388];   // Q, later C1
    __shared__ float Ks[KCL * 388];   // K, later V
    __shared__ float ewt[NEXP * 388]; // ew transposed [e][d]
    __shared__ float Ss[KCL * 17];
    __shared__ float hws[KCL * 9];
    __shared__ float rds[NEXP];
    __shared__ float Ls[NEXP * NEXP];
    const int b = blockIdx.x, tid = threadIdx.x;
    for (int idx = tid; idx < KCL * DM; idx += 256) {
        int i = idx / DM, d = idx - i * DM;
        size_t g = (size_t)b * KCL * DM + idx;
        Qs[i * 388 + d] = Qg[g];
        Ks[i * 388 + d] = Kg[g];
    }
    for (int idx = tid; idx < DM * NEXP; idx += 256) {
        int d = idx >> 3, e = idx & 7;
        ewt[e * 388 + d] = ew[idx];
    }
    __syncthreads();
    {   // S = Q K^T / sqrt(D), softmax rows
        int i = tid >> 4, j = tid & 15;
        float acc = 0.f;
        for (int d = 0; d < DM; d += 4) {
            float4 q = *(const float4*)&Qs[i * 388 + d];
            float4 k = *(const float4*)&Ks[j * 388 + d];
            acc += q.x * k.x + q.y * k.y + q.z * k.z + q.w * k.w;
        }
        float s = acc / sqrtf((float)DM);
        float mx = s;
#pragma unroll
        for (int off = 8; off >= 1; off >>= 1) mx = fmaxf(mx, __shfl_xor(mx, off));
        float p = expf(s - mx);
        float sm = p;
#pragma unroll
        for (int off = 8; off >= 1; off >>= 1) sm += __shfl_xor(sm, off);
        Ss[i * 17 + j] = p / sm;
    }
    __syncthreads();
    for (int idx = tid; idx < KCL * DM; idx += 256) {
        int i = idx / DM, d = idx - i * DM;
        Ks[i * 388 + d] = Vg[(size_t)b * KCL * DM + idx];
    }
    __syncthreads();
    for (int idx = tid; idx < KCL * DM; idx += 256) {
        int i = idx / DM, d = idx - i * DM;
        float acc = 0.f;
#pragma unroll
        for (int j = 0; j < KCL; ++j) acc += Ss[i * 17 + j] * Ks[j * 388 + d];
        Qs[i * 388 + d] = acc;
    }
    __syncthreads();
    if (tid < 128) {
        int e = tid >> 4, i = tid & 15;
        float l = 0.f;
        for (int d4 = 0; d4 < DM / 4; ++d4) {
            float4 q = *(const float4*)&Qs[i * 388 + d4 * 4];
            float4 w = *(const float4*)&ewt[e * 388 + d4 * 4];
            l += q.x * w.x + q.y * w.y + q.z * w.z + q.w * w.w;
        }
        l += eb[e];
        float mx = l;
#pragma unroll
        for (int off = 8; off >= 1; off >>= 1) mx = fmaxf(mx, __shfl_xor(mx, off));
        float p = expf(l - mx);
        float sm = p;
#pragma unroll
        for (int off = 8; off >= 1; off >>= 1) sm += __shfl_xor(sm, off);
        float h = p / sm;
        hws[i * 9 + e] = h;
        float sd = h;
#pragma unroll
        for (int off = 8; off >= 1; off >>= 1) sd += __shfl_xor(sd, off);
        if (i == 0) rds[e] = 1.0f / sqrtf(sd);
    }
    __syncthreads();
    if (tid < 64) {
        int e = tid >> 3, f = tid & 7;
        float gsum = 0.f;
#pragma unroll
        for (int k = 0; k < KCL; ++k) gsum += hws[k * 9 + e] * hws[k * 9 + f];
        Ls[e * 8 + f] = ((e == f) ? 1.0f : 0.0f) - rds[e] * gsum;
    }
    __syncthreads();
    for (int idx = tid; idx < KCL * DM; idx += 256) {
        int i = idx / DM, d = idx - i * DM;
        float acc = 0.f;
        if (i < NEXP) {
#pragma unroll
            for (int j = 0; j < NEXP; ++j) acc += Ls[i * 8 + j] * Qs[j * 388 + d];
        }
        c2[(size_t)b * KCL * DM + idx] = acc;
    }
}

// ---------------------------------------------------------------------------
// K6: normalize rows, sim = nc @ nc^T, OR (sim>0.9) into global mask
// ---------------------------------------------------------------------------
__global__ __launch_bounds__(256) void simmask_kernel(const float* __restrict__ c4,
                                                      int* __restrict__ mask) {
    __shared__ float Cs[KCL * 388];
    __shared__ float rns[KCL];
    const int b = blockIdx.x, tid = threadIdx.x;
    for (int idx = tid; idx < KCL * DM; idx += 256) {
        int i = idx / DM, d = idx - i * DM;
        Cs[i * 388 + d] = c4[(size_t)b * KCL * DM + idx];
    }
    __syncthreads();
    {
        int i = tid >> 4, s = tid & 15;
        float ss = 0.f;
        for (int t = 0; t < 24; ++t) { float v = Cs[i * 388 + s + 16 * t]; ss += v * v; }
#pragma unroll
        for (int off = 8; off >= 1; off >>= 1) ss += __shfl_xor(ss, off);
        if (s == 0) rns[i] = 1.0f / fmaxf(sqrtf(ss), 1e-12f);
    }
    __syncthreads();
    for (int idx = tid; idx < KCL * DM; idx += 256) {
        int i = idx / DM, d = idx - i * DM;
        Cs[i * 388 + d] *= rns[i];
    }
    __syncthreads();
    {
        int i = tid >> 4, j = tid & 15;
        if (j > i) {
            float dp = 0.f;
            for (int d = 0; d < DM; d += 4) {
                float4 a = *(const float4*)&Cs[i * 388 + d];
                float4 c = *(const float4*)&Cs[j * 388 + d];
                dp += a.x * c.x + a.y * c.y + a.z * c.z + a.w * c.w;
            }
            if (dp > 0.9f) atomicOr(&mask[i * KCL + j], 1);
        }
    }
}

// ---------------------------------------------------------------------------
// K7: sequential pairwise merge + mean + feedback gate -> c5
// ---------------------------------------------------------------------------
__global__ __launch_bounds__(256) void merge_fb_kernel(
        const float* __restrict__ c4, const int* __restrict__ mask,
        const float* __restrict__ fbw, const float* __restrict__ fbb,
        const float* __restrict__ fgw, const float* __restrict__ fgb,
        float* __restrict__ c5) {
    __shared__ int   mk[256];
    __shared__ float gs[DM];
    __shared__ float wred[3];
    __shared__ float gatev;
    const int b = blockIdx.x, tid = threadIdx.x;
    mk[tid] = mask[tid];
    const bool act = tid < 192;
    const int t = tid;
    float2 v[KCL];
    if (act) {
#pragma unroll
        for (int i = 0; i < KCL; ++i)
            v[i] = *(const float2*)(c4 + (size_t)b * KCL * DM + i * DM + 2 * t);
    }
    __syncthreads();
    if (act) {
#pragma unroll
        for (int i = 0; i < KCL; ++i)
#pragma unroll
            for (int j = i + 1; j < KCL; ++j)
                if (mk[i * KCL + j]) {
                    float mx = 0.5f * (v[i].x + v[j].x);
                    float my = 0.5f * (v[i].y + v[j].y);
                    v[i].x = mx; v[i].y = my; v[j].x = mx; v[j].y = my;
                }
    }
    float2 gv = {0.f, 0.f};
    if (act) {
#pragma unroll
        for (int i = 0; i < KCL; ++i) { gv.x += v[i].x; gv.y += v[i].y; }
        gv.x *= 0.0625f; gv.y *= 0.0625f;
        gs[2 * t] = gv.x; gs[2 * t + 1] = gv.y;
    }
    float pg = act ? (gv.x * fgw[2 * t] + gv.y * fgw[2 * t + 1]) : 0.f;
#pragma unroll
    for (int off = 32; off >= 1; off >>= 1) pg += __shfl_xor(pg, off);
    if (act && (tid & 63) == 0) wred[tid >> 6] = pg;
    __syncthreads();
    if (tid == 0) {
        float d = wred[0] + wred[1] + wred[2] + fgb[0];
        gatev = 1.0f / (1.0f + expf(-d));
    }
    __syncthreads();
    if (act) {
        float fx = fbb[2 * t], fy = fbb[2 * t + 1];
        for (int j = 0; j < DM; ++j) {
            float gj = gs[j];
            const float2 w = *(const float2*)(fbw + (size_t)j * DM + 2 * t);
            fx += gj * w.x; fy += gj * w.y;
        }
        float gt = gatev;
#pragma unroll
        for (int i = 0; i < KCL; ++i) {
            float2 o = {v[i].x + fx * gt, v[i].y + fy * gt};
            *(float2*)(c5 + (size_t)b * KCL * DM + i * DM + 2 * t) = o;
        }
    }
}

// ---------------------------------------------------------------------------
// K8: classifier, split-K with fp32 atomics. out pre-initialized with cb.
// ---------------------------------------------------------------------------
__global__ __launch_bounds__(256) void cls_kernel(const float* __restrict__ A,
                                                  const float* __restrict__ Wt,
                                                  float* __restrict__ out) {
    __shared__ float As[32 * 32];
    __shared__ float Ws[32 * 128];
    const int n0 = blockIdx.x * 128;
    const int m0 = blockIdx.y * 32;
    const int k0 = blockIdx.z * 768;
    const int tid = threadIdx.x;
    const int rg = tid >> 5, cg = tid & 31;
    const int arow = tid >> 3, akg = tid & 7;
    float acc[4][4];
#pragma unroll
    for (int r = 0; r < 4; ++r)
#pragma unroll
        for (int j = 0; j < 4; ++j) acc[r][j] = 0.f;

    for (int kc = k0; kc < k0 + 768; kc += 32) {
        float4 av = *(const float4*)(A + (size_t)(m0 + arow) * (KCL * DM) + kc + akg * 4);
        As[(akg * 4 + 0) * 32 + arow] = av.x;
        As[(akg * 4 + 1) * 32 + arow] = av.y;
        As[(akg * 4 + 2) * 32 + arow] = av.z;
        As[(akg * 4 + 3) * 32 + arow] = av.w;
#pragma unroll
        for (int ti = 0; ti < 4; ++ti) {
            int s = tid + ti * 256;
            int kk = s >> 5, c4i = s & 31;
            int col = n0 + c4i * 4;
            float4 wv = make_float4(0.f, 0.f, 0.f, 0.f);
            if (col < NCLS) wv = *(const float4*)(Wt + (size_t)(kc + kk) * NCLS + col);
            *(float4*)&Ws[kk * 128 + c4i * 4] = wv;
        }
        __syncthreads();
#pragma unroll 16
        for (int kk = 0; kk < 32; ++kk) {
            float4 a = *(const float4*)&As[kk * 32 + rg * 4];
            float4 w = *(const float4*)&Ws[kk * 128 + cg * 4];
            float ar[4] = {a.x, a.y, a.z, a.w};
            float wr[4] = {w.x, w.y, w.z, w.w};
#pragma unroll
            for (int r = 0; r < 4; ++r)
#pragma unroll
                for (int j = 0; j < 4; ++j) acc[r][j] += ar[r] * wr[j];
        }
        __syncthreads();
    }
    int col = n0 + cg * 4;
    if (col < NCLS) {
#pragma unroll
        for (int r = 0; r < 4; ++r) {
            int row = m0 + rg * 4 + r;
#pragma unroll
            for (int j = 0; j < 4; ++j)
                atomicAdd(&out[(size_t)row * NCLS + col + j], acc[r][j]);
        }
    }
}

// ---------------------------------------------------------------------------
extern "C" void kernel_launch(void* const* d_in, const int* in_sizes, int n_in,
                              void* d_out, int out_size, void* d_ws, size_t ws_size,
                              hipStream_t stream) {
    const float* x   = (const float*)d_in[0];
    const float* pw  = (const float*)d_in[1];
    const float* pb  = (const float*)d_in[2];
    const float* lng = (const float*)d_in[3];
    const float* lnb = (const float*)d_in[4];
    const float* pos = (const float*)d_in[5];
    const float* qw  = (const float*)d_in[6];
    const float* qb  = (const float*)d_in[7];
    const float* kw  = (const float*)d_in[8];
    const float* kb  = (const float*)d_in[9];
    const float* vw  = (const float*)d_in[10];
    const float* vb  = (const float*)d_in[11];
    const float* ew  = (const float*)d_in[12];
    const float* eb  = (const float*)d_in[13];
    const float* nw  = (const float*)d_in[14];
    const float* nb  = (const float*)d_in[15];
    const float* m1w = (const float*)d_in[16];
    const float* m1b = (const float*)d_in[17];
    const float* m2w = (const float*)d_in[18];
    const float* m2b = (const float*)d_in[19];
    const float* fbw = (const float*)d_in[20];
    const float* fbb = (const float*)d_in[21];
    const float* fgw = (const float*)d_in[22];
    const float* fgb = (const float*)d_in[23];
    const float* cw  = (const float*)d_in[24];
    const float* cb  = (const float*)d_in[25];
    float* out = (float*)d_out;
    float* ws  = (float*)d_ws;

    // workspace layout (floats)
    float* pn_   = ws;                    // 128*196*384 = 9,633,792
    float* pnsq_ = ws + 9633792;          // 25,088
    float* c0_   = ws + 9658880;          // 786,432 (clusters0; later c5)
    float* Q_    = ws + 10445312;         // 786,432 (later c3)
    float* K_    = ws + 11231744;         // 786,432 (later h)
    float* V_    = ws + 12018176;         // 786,432 (later c4)
    float* c2_   = ws + 12804608;         // 786,432
    int*   mask_ = (int*)(ws + 13591040); // 256 ints
    float* c3_ = Q_;
    float* h_  = K_;
    float* c4_ = V_;
    float* c5_ = c0_;

    init_kernel<<<501, 256, 0, stream>>>(cb, out, mask_);
    patch_ln_kernel<<<392, 512, 0, stream>>>(x, pw, pb, lng, lnb, pn_, pnsq_);

    kmeans_fused_kernel<<<NBATCH, 1024, 0, stream>>>(pn_, pnsq_, pos, c0_);

    gemm_qkv_kernel<<<dim3(3, 64), 256, 0, stream>>>(c0_, qw, kw, vw, qb, kb, vb,
                                                     Q_, K_, V_);
    attn_spectral_kernel<<<NBATCH, 256, 0, stream>>>(Q_, K_, V_, ew, eb, c2_);
    gemm_kernel<0><<<dim3(3, 64), 256, 0, stream>>>(c2_, nw, nb, c3_, 2048, DM, DM);
    gemm_kernel<1><<<dim3(3, 64), 256, 0, stream>>>(c3_, m1w, m1b, h_, 2048, DM, DM);
    gemm_kernel<0><<<dim3(3, 64), 256, 0, stream>>>(h_, m2w, m2b, c4_, 2048, DM, DM);
    simmask_kernel<<<NBATCH, 256, 0, stream>>>(c4_, mask_);
    merge_fb_kernel<<<NBATCH, 256, 0, stream>>>(c4_, mask_, fbw, fbb, fgw, fgb, c5_);
    cls_kernel<<<dim3(8, 4, 8), 256, 0, stream>>>(c5_, cw, out);
}